// Round 6
// baseline (582.954 us; speedup 1.0000x reference)
//
#include <hip/hip_runtime.h>

#define NN 128
#define HH 128
#define BB 2
#define KT 4
#define EE 16256
#define TT 9   // T-1 prediction steps

typedef __bf16 v8bf __attribute__((ext_vector_type(8)));
typedef float v4f __attribute__((ext_vector_type(4)));

__device__ __forceinline__ float tanh_fast(float x) {
  // tanh(x) = 1 - 2/(e^{2x}+1); v_exp + v_rcp
  return 1.0f - __fdividef(2.0f, __expf(2.0f * x) + 1.0f);
}
__device__ __forceinline__ float sigmoid_fast(float x) {
  return __fdividef(1.0f, 1.0f + __expf(-x));
}
__device__ __forceinline__ unsigned short f2bf(float f) {  // RNE f32->bf16
  unsigned int u = __float_as_uint(f);
  u += 0x7FFFu + ((u >> 16) & 1u);
  return (unsigned short)(u >> 16);
}

// prep: W1hi/W1lo[(k*2+u)*128+g][h] = split-bf16 of W_msg1[k][g][u*128+h]
//       W2bf[k][g][h]               = bf16(W_msg2[k][g][h])
//       relp[b][n][k][r]            = rel_type[(b, e=r*127+idx), k]  (coalesced)
__global__ void prep_kernel(const float* __restrict__ W_msg1,
                            const float* __restrict__ W_msg2,
                            const float* __restrict__ rel_type,
                            unsigned short* __restrict__ W1hi,
                            unsigned short* __restrict__ W1lo,
                            unsigned short* __restrict__ W2bf,
                            float* __restrict__ relp) {
  int idx = blockIdx.x * 256 + threadIdx.x;  // 0..131071
  {
    int h = idx & 127, g = (idx >> 7) & 127, ku = idx >> 14;
    int k = ku >> 1, u = ku & 1;
    float w = W_msg1[(k * 128 + g) * 256 + u * 128 + h];
    unsigned short hi = f2bf(w);
    float whi = __uint_as_float(((unsigned int)hi) << 16);
    W1hi[idx] = hi;
    W1lo[idx] = f2bf(w - whi);   // residual: hi+lo ~ fp32-exact
  }
  if (idx < 65536) W2bf[idx] = f2bf(W_msg2[idx]);
  {
    int r = idx & 127, k = (idx >> 7) & 3, n = (idx >> 9) & 127, b = idx >> 16;
    float v = 0.f;
    if (r != n) {
      int e = r * 127 + (n < r ? n : n - 1);  // sender-major edge order (np.where)
      v = rel_type[(b * EE + e) * KT + k];
    }
    relp[idx] = v;
  }
}

// One time step. Block = (b, receiver n). 512 threads = 8 waves.
// Stage W2 (all k) + per-block vectors ONCE -> barrier-free k-loop with
// register-built A-fragments -> reduce -> GRU -> output MLP -> UV via
// split-bf16 MFMA (fp32-accurate).
__global__ __launch_bounds__(512)
void step_kernel(const float* __restrict__ data,
                 const float* __restrict__ b_msg1,
                 const float* __restrict__ b_msg2,
                 const float* __restrict__ W_hr,
                 const float* __restrict__ W_hi_,
                 const float* __restrict__ W_hh,
                 const float* __restrict__ W_ir, const float* __restrict__ b_ir,
                 const float* __restrict__ W_ii, const float* __restrict__ b_ii,
                 const float* __restrict__ W_in, const float* __restrict__ b_in,
                 const float* __restrict__ W_o1, const float* __restrict__ b_o1,
                 const float* __restrict__ W_o2, const float* __restrict__ b_o2,
                 const float* __restrict__ W_o3, const float* __restrict__ b_o3,
                 const unsigned short* __restrict__ W1hi,
                 const unsigned short* __restrict__ W1lo,
                 const unsigned short* __restrict__ W2bf,
                 const float* __restrict__ relp,
                 float* __restrict__ hidden,
                 const float* __restrict__ UVin,
                 float* __restrict__ UVout,
                 float* __restrict__ outp,
                 int t) {
  __shared__ unsigned short w2_lds[65536];  // 4 x 128 x 128 bf16, XOR-swizzled per plane
  __shared__ float ub_lds[512];             // [k][h]: U[k,b,n,h] + b_msg1[k,h]
  __shared__ float b2_lds[512];             // [k][g]
  __shared__ float rel_lds[512];            // [k][r]
  __shared__ float colsum[8][128];
  __shared__ float agg_lds[128];
  __shared__ float hid_lds[128];
  __shared__ float hn_lds[128];
  __shared__ float ins_lds[6];
  __shared__ float g_r[128], g_i[128], g_hh[128], g_in[128];
  __shared__ float p1_lds[128], p2_lds[128];

  const int tid = threadIdx.x;
  const int lane = tid & 63;
  const int wave = tid >> 6;  // owns A rows [wave*16, wave*16+16)
  const int b = blockIdx.x >> 7;
  const int n = blockIdx.x & 127;

  // ---- stage everything once ----
  {
    const uint4* w2g = (const uint4*)W2bf;
#pragma unroll
    for (int i = 0; i < 16; ++i) {
      int cid = tid + i * 512;            // 8192 chunks of 16B
      int plane = cid >> 11, c2 = cid & 2047;
      int g = c2 >> 4, cc = c2 & 15;
      uint4 v = w2g[cid];
      int off = (plane << 15) + (g << 8) + (cc << 4);
      off ^= (g & 7) << 4;
      *(uint4*)((char*)w2_lds + off) = v;
    }
    int k = tid >> 7, h = tid & 127;
    ub_lds[tid] = UVin[(((k * 2 + 0) * BB + b) * NN + n) * HH + h] + b_msg1[tid];
    b2_lds[tid] = b_msg2[tid];
    rel_lds[tid] = relp[(b * NN + n) * (KT * NN) + tid];
  }
  __syncthreads();

  float acc_all[8][4];
#pragma unroll
  for (int c = 0; c < 8; ++c)
#pragma unroll
    for (int r = 0; r < 4; ++r) acc_all[c][r] = 0.f;

  // ---- barrier-free k loop ----
  for (int k = 0; k < KT; ++k) {
    // A-fragments in registers: tanh(U[n] + V[r] + b1), exactly the lane's slice
    const float* vbase = UVin + (((k * 2 + 1) * BB + b) * NN + (wave * 16 + (lane & 15))) * HH;
    v8bf af[4];
#pragma unroll
    for (int ks = 0; ks < 4; ++ks) {
      int c0 = ks * 32 + ((lane >> 4) << 3);
      float4 v0 = *(const float4*)(vbase + c0);
      float4 v1 = *(const float4*)(vbase + c0 + 4);
      const float* up = ub_lds + k * 128 + c0;
      float4 u0 = *(const float4*)(up);
      float4 u1 = *(const float4*)(up + 4);
      af[ks][0] = (__bf16)tanh_fast(u0.x + v0.x);
      af[ks][1] = (__bf16)tanh_fast(u0.y + v0.y);
      af[ks][2] = (__bf16)tanh_fast(u0.z + v0.z);
      af[ks][3] = (__bf16)tanh_fast(u0.w + v0.w);
      af[ks][4] = (__bf16)tanh_fast(u1.x + v1.x);
      af[ks][5] = (__bf16)tanh_fast(u1.y + v1.y);
      af[ks][6] = (__bf16)tanh_fast(u1.z + v1.z);
      af[ks][7] = (__bf16)tanh_fast(u1.w + v1.w);
    }
    // layer2: out[r][g] = sum_h msg1[r][h] * W2[g][h]
    v4f acck[8];
#pragma unroll
    for (int c = 0; c < 8; ++c) acck[c] = (v4f){0.f, 0.f, 0.f, 0.f};
#pragma unroll
    for (int ks = 0; ks < 4; ++ks) {
#pragma unroll
      for (int c = 0; c < 8; ++c) {
        int g = c * 16 + (lane & 15);
        int boff = (k << 15) + (g << 8) + (ks << 6) + ((lane >> 4) << 4);
        boff ^= (g & 7) << 4;
        v8bf bfrag = *(const v8bf*)((const char*)w2_lds + boff);
        acck[c] = __builtin_amdgcn_mfma_f32_16x16x32_bf16(af[ks], bfrag, acck[c], 0, 0, 0);
      }
    }
    // epilogue: tanh(+b2), weight by rel_type, accumulate over k
#pragma unroll
    for (int c = 0; c < 8; ++c) {
      float bb = b2_lds[k * 128 + c * 16 + (lane & 15)];
#pragma unroll
      for (int rg = 0; rg < 4; ++rg) {
        int rowg = wave * 16 + ((lane >> 4) << 2) + rg;  // D: row=(l>>4)*4+reg
        acc_all[c][rg] += tanh_fast(acck[c][rg] + bb) * rel_lds[k * 128 + rowg];
      }
    }
  }

  // ---- reduce over edge rows -> agg[b,n,:] ----
#pragma unroll
  for (int c = 0; c < 8; ++c) {
    float s = acc_all[c][0] + acc_all[c][1] + acc_all[c][2] + acc_all[c][3];
    s += __shfl_xor(s, 16);
    s += __shfl_xor(s, 32);
    if ((lane >> 4) == 0) colsum[wave][c * 16 + lane] = s;
  }
  __syncthreads();
  if (tid < 128) {
    float s = 0.f;
#pragma unroll
    for (int w = 0; w < 8; ++w) s += colsum[w][tid];
    agg_lds[tid] = s * (1.0f / 24.0f);   // /K then /NIN
    hid_lds[tid] = hidden[(b * NN + n) * HH + tid];
  }
  if (tid >= 128 && tid < 134) ins_lds[tid - 128] = data[((b * 10 + t) * NN + n) * 6 + (tid - 128)];
  __syncthreads();

  // ---- GRU gates ----
  {
    int h = tid >> 2, q = tid & 3;
    const float4* whr = (const float4*)(W_hr + h * 128 + q * 32);
    const float4* whi = (const float4*)(W_hi_ + h * 128 + q * 32);
    const float4* whh = (const float4*)(W_hh + h * 128 + q * 32);
    const float4* ag4 = (const float4*)(agg_lds + q * 32);
    float phr = 0.f, phi = 0.f, phh = 0.f;
#pragma unroll
    for (int j = 0; j < 8; ++j) {
      float4 a = ag4[j];
      float4 wr = whr[j], wi = whi[j], wh = whh[j];
      phr += wr.x * a.x + wr.y * a.y + wr.z * a.z + wr.w * a.w;
      phi += wi.x * a.x + wi.y * a.y + wi.z * a.z + wi.w * a.w;
      phh += wh.x * a.x + wh.y * a.y + wh.z * a.z + wh.w * a.w;
    }
    phr += __shfl_xor(phr, 1); phr += __shfl_xor(phr, 2);
    phi += __shfl_xor(phi, 1); phi += __shfl_xor(phi, 2);
    phh += __shfl_xor(phh, 1); phh += __shfl_xor(phh, 2);
    if (q == 0) {
      float dr = b_ir[h], di = b_ii[h], dn = b_in[h];
#pragma unroll
      for (int j = 0; j < 6; ++j) {
        float iv = ins_lds[j];
        dr += W_ir[h * 6 + j] * iv;
        di += W_ii[h * 6 + j] * iv;
        dn += W_in[h * 6 + j] * iv;
      }
      g_r[h] = dr + phr; g_i[h] = di + phi; g_hh[h] = phh; g_in[h] = dn;
    }
  }
  __syncthreads();
  if (tid < 128) {
    float r = sigmoid_fast(g_r[tid]);
    float ii = sigmoid_fast(g_i[tid]);
    float ng = tanh_fast(g_in[tid] + r * g_hh[tid]);
    float hn = (1.0f - ii) * ng + ii * hid_lds[tid];
    hn_lds[tid] = hn;
    hidden[(b * NN + n) * HH + tid] = hn;  // row owned by this block
  }
  __syncthreads();

  // ---- output MLP ----
  {
    int h = tid >> 2, q = tid & 3;
    const float4* w4 = (const float4*)(W_o1 + h * 128 + q * 32);
    const float4* a4 = (const float4*)(hn_lds + q * 32);
    float p = 0.f;
#pragma unroll
    for (int j = 0; j < 8; ++j) {
      float4 w = w4[j]; float4 a = a4[j];
      p += w.x * a.x + w.y * a.y + w.z * a.z + w.w * a.w;
    }
    p += __shfl_xor(p, 1); p += __shfl_xor(p, 2);
    if (q == 0) p1_lds[h] = fmaxf(p + b_o1[h], 0.f);
  }
  __syncthreads();
  {
    int h = tid >> 2, q = tid & 3;
    const float4* w4 = (const float4*)(W_o2 + h * 128 + q * 32);
    const float4* a4 = (const float4*)(p1_lds + q * 32);
    float p = 0.f;
#pragma unroll
    for (int j = 0; j < 8; ++j) {
      float4 w = w4[j]; float4 a = a4[j];
      p += w.x * a.x + w.y * a.y + w.z * a.z + w.w * a.w;
    }
    p += __shfl_xor(p, 1); p += __shfl_xor(p, 2);
    if (q == 0) p2_lds[h] = fmaxf(p + b_o2[h], 0.f);
  }
  __syncthreads();
  if (tid < 48) {
    int i = tid >> 3, oc = tid & 7;
    const float4* w4 = (const float4*)(W_o3 + i * 128 + oc * 16);
    const float4* a4 = (const float4*)(p2_lds + oc * 16);
    float p = 0.f;
#pragma unroll
    for (int j = 0; j < 4; ++j) {
      float4 w = w4[j]; float4 a = a4[j];
      p += w.x * a.x + w.y * a.y + w.z * a.z + w.w * a.w;
    }
    p += __shfl_xor(p, 1); p += __shfl_xor(p, 2); p += __shfl_xor(p, 4);
    if (oc == 0) outp[((b * NN + n) * TT + t) * 6 + i] = ins_lds[i] + p + b_o3[i];
  }

  // ---- UV for next step via split-bf16 MFMA (fp32-accurate) ----
  // x = hi + lo; a*b ~ a_hi*b_hi + a_lo*b_hi + a_hi*b_lo (lo*lo ~ 2^-18, dropped)
  {
    v8bf hf_hi[4], hf_lo[4];
#pragma unroll
    for (int q = 0; q < 4; ++q) {
      int c0 = q * 32 + ((lane >> 4) << 3);
      bool live = (lane & 15) == 0;
#pragma unroll
      for (int j = 0; j < 8; ++j) {
        float a = live ? hn_lds[c0 + j] : 0.f;
        __bf16 ah = (__bf16)a;
        hf_hi[q][j] = ah;
        hf_lo[q][j] = (__bf16)(a - (float)ah);
      }
    }
#pragma unroll
    for (int c = 0; c < 8; ++c) {
      int gg = (wave * 8 + c) * 16 + (lane & 15);  // 0..1023 = (k*2+u)*128+g
      v4f acc = (v4f){0.f, 0.f, 0.f, 0.f};
#pragma unroll
      for (int q = 0; q < 4; ++q) {
        int hoff = q * 32 + ((lane >> 4) << 3);
        v8bf bhi = *(const v8bf*)(W1hi + (size_t)gg * 128 + hoff);
        v8bf blo = *(const v8bf*)(W1lo + (size_t)gg * 128 + hoff);
        acc = __builtin_amdgcn_mfma_f32_16x16x32_bf16(hf_hi[q], bhi, acc, 0, 0, 0);
        acc = __builtin_amdgcn_mfma_f32_16x16x32_bf16(hf_lo[q], bhi, acc, 0, 0, 0);
        acc = __builtin_amdgcn_mfma_f32_16x16x32_bf16(hf_hi[q], blo, acc, 0, 0, 0);
      }
      if ((lane >> 4) == 0) {  // D row 0 = reg 0 of lanes 0..15
        int kh = gg >> 7, g = gg & 127;
        UVout[((kh * BB + b) * NN + n) * HH + g] = acc[0];
      }
    }
  }
}

extern "C" void kernel_launch(void* const* d_in, const int* in_sizes, int n_in,
                              void* d_out, int out_size, void* d_ws, size_t ws_size,
                              hipStream_t stream) {
  const float* data     = (const float*)d_in[0];
  const float* rel_type = (const float*)d_in[1];
  // d_in[2]=rel_rec, d_in[3]=rel_send: deterministic one-hot, handled analytically
  const float* W_msg1 = (const float*)d_in[4];
  const float* b_msg1 = (const float*)d_in[5];
  const float* W_msg2 = (const float*)d_in[6];
  const float* b_msg2 = (const float*)d_in[7];
  const float* W_hr = (const float*)d_in[8];
  const float* W_hi = (const float*)d_in[9];
  const float* W_hh = (const float*)d_in[10];
  const float* W_ir = (const float*)d_in[11];
  const float* b_ir = (const float*)d_in[12];
  const float* W_ii = (const float*)d_in[13];
  const float* b_ii = (const float*)d_in[14];
  const float* W_in = (const float*)d_in[15];
  const float* b_in = (const float*)d_in[16];
  const float* W_o1 = (const float*)d_in[17];
  const float* b_o1 = (const float*)d_in[18];
  const float* W_o2 = (const float*)d_in[19];
  const float* b_o2 = (const float*)d_in[20];
  const float* W_o3 = (const float*)d_in[21];
  const float* b_o3 = (const float*)d_in[22];
  float* outp = (float*)d_out;

  char* ws = (char*)d_ws;
  float* hidden        = (float*)(ws);                       // 128 KiB
  float* UVa           = (float*)(ws + 131072);              // 1 MiB
  float* UVb           = (float*)(ws + 1179648);             // 1 MiB
  unsigned short* W1hi = (unsigned short*)(ws + 2228224);    // 256 KiB
  unsigned short* W1lo = (unsigned short*)(ws + 2490368);    // 256 KiB
  unsigned short* W2bf = (unsigned short*)(ws + 2752512);    // 128 KiB
  float* relp          = (float*)(ws + 2883584);             // 512 KiB

  hipMemsetAsync(hidden, 0, 131072, stream);  // hidden0 = 0
  hipMemsetAsync(UVa, 0, 1048576, stream);    // U,V of hidden0 = 0
  prep_kernel<<<512, 256, 0, stream>>>(W_msg1, W_msg2, rel_type, W1hi, W1lo, W2bf, relp);

  for (int t = 0; t < TT; ++t) {
    float* uvin = (t & 1) ? UVb : UVa;
    float* uvout = (t & 1) ? UVa : UVb;
    step_kernel<<<BB * NN, 512, 0, stream>>>(
        data, b_msg1, b_msg2, W_hr, W_hi, W_hh,
        W_ir, b_ir, W_ii, b_ii, W_in, b_in,
        W_o1, b_o1, W_o2, b_o2, W_o3, b_o3,
        W1hi, W1lo, W2bf, relp, hidden, uvin, uvout, outp, t);
  }
}